// Round 6
// baseline (139.657 us; speedup 1.0000x reference)
//
#include <hip/hip_runtime.h>

#define B_   16
#define NK_  256
#define NQ_  256
#define DK_  256
#define H_   128
#define DV_  256

// 2*log2(e): features prescaled so exp2(C2X*x) = e^{2x}
#define C2X 2.8853900817779268f
// log2(e) for softmax exp
#define L2E 1.4426950408889634f

typedef float f4 __attribute__((ext_vector_type(4)));

__device__ __forceinline__ float exp2_fast(float x) { return __builtin_amdgcn_exp2f(x); }
__device__ __forceinline__ float rcp_fast(float x)  { return __builtin_amdgcn_rcpf(x); }

// ---------------------------------------------------------------------------
// Kernel A: projections -> EXponentiated features.  (unchanged, known-good)
//   blocks 0..127   : kfE[b][k][h]        = exp2(C2X * (key  @ Wk))
//   blocks 128..255 : qE4[b][h/4][q][4]   = exp2(C2X * (query @ Wq))
// ---------------------------------------------------------------------------
__global__ __launch_bounds__(256) void proj_kernel(
    const float* __restrict__ key, const float* __restrict__ query,
    const float* __restrict__ Wk,  const float* __restrict__ Wq,
    float* __restrict__ kfE, float* __restrict__ qE4)
{
    __shared__ alignas(16) float A_s[32 * 256];   // 32 KB
    __shared__ alignas(16) float W_s[64 * 128];   // 32 KB

    const int blk = blockIdx.x;
    const int tid = threadIdx.x;
    const bool isQ = blk >= 128;
    const int rb = (blk & 127) * 32;              // flat row base (b*256 + row)

    const float* __restrict__ A = isQ ? query : key;
    const float* __restrict__ W = isQ ? Wq : Wk;

    {
        const f4* src = (const f4*)(A + (size_t)rb * DK_);
        f4* dst = (f4*)A_s;
#pragma unroll
        for (int j = 0; j < 8; ++j) dst[tid + 256 * j] = src[tid + 256 * j];
    }

    const int rg = (tid >> 5) * 4;                // row group: 4 rows
    const int c4 = (tid & 31) * 4;                // col base:  4 cols

    f4 acc[4];
#pragma unroll
    for (int r = 0; r < 4; ++r) acc[r] = (f4){0.f, 0.f, 0.f, 0.f};

    for (int kc = 0; kc < DK_; kc += 64) {
        __syncthreads();
        {
            const f4* wsrc = (const f4*)(W + (size_t)kc * H_);
            f4* wdst = (f4*)W_s;
#pragma unroll
            for (int j = 0; j < 8; ++j) wdst[tid + 256 * j] = wsrc[tid + 256 * j];
        }
        __syncthreads();
#pragma unroll 2
        for (int k = 0; k < 64; k += 4) {
            f4 w0 = *(const f4*)(W_s + (k + 0) * H_ + c4);
            f4 w1 = *(const f4*)(W_s + (k + 1) * H_ + c4);
            f4 w2 = *(const f4*)(W_s + (k + 2) * H_ + c4);
            f4 w3 = *(const f4*)(W_s + (k + 3) * H_ + c4);
#pragma unroll
            for (int r = 0; r < 4; ++r) {
                f4 a = *(const f4*)(A_s + (rg + r) * 256 + kc + k);
                acc[r] += a[0] * w0;
                acc[r] += a[1] * w1;
                acc[r] += a[2] * w2;
                acc[r] += a[3] * w3;
            }
        }
    }

    if (!isQ) {
        float* dst = kfE + (size_t)(rb + rg) * H_ + c4;
#pragma unroll
        for (int r = 0; r < 4; ++r) {
            f4 o;
#pragma unroll
            for (int cc = 0; cc < 4; ++cc) o[cc] = exp2_fast(C2X * acc[r][cc]);
            *(f4*)(dst + (size_t)r * H_) = o;
        }
    } else {
        const int b  = rb >> 8;
        const int q0 = (rb & 255) + rg;
        f4* dst = (f4*)qE4 + ((size_t)(b * 32 + (c4 >> 2))) * NQ_ + q0;
#pragma unroll
        for (int r = 0; r < 4; ++r) {
            f4 o;
#pragma unroll
            for (int cc = 0; cc < 4; ++cc) o[cc] = exp2_fast(C2X * acc[r][cc]);
            dst[r] = o;
        }
    }
}

// ---------------------------------------------------------------------------
// Kernel B1: unnormalized exp-scores.  1024 blocks x 256 threads, NO LDS,
// NO barriers.  Block = (b, 4 k-rows); wave w = q-chunk (w+rot)&3 for ALL
// 4 k-rows (eq held in registers -> eq L2 traffic /4 vs R5).  Waves whose
// chunk is masked out retire immediately (no barrier coupling -> scheduler
// backfills from the 1024-block queue; rot spreads idles across SIMDs).
// No-max softmax: |score| <= sum|wv| ~ 9, exp in [1e-4, 8e3] -> safe in f32.
// Writes E[b][k][q] = exp(score) (0 for q >= valid), coalesced per k-row.
// ---------------------------------------------------------------------------
__global__ __launch_bounds__(256) void score_kernel(
    const float* __restrict__ kfE, const float* __restrict__ qE4,
    const int* __restrict__ vlens, const float* __restrict__ wv,
    float* __restrict__ E)
{
    const int x    = blockIdx.x;
    const int qu   = x >> 8;                       // dispatch round 0..3
    const int xi   = x & 255;
    const int b    = (xi + (qu << 2)) & 15;        // b rotated for balance
    const int kt   = (xi >> 4) + (qu << 4);        // 0..63
    const int k0   = kt << 2;
    const int rot  = ((xi >> 4) + qu) & 3;
    const int tid  = threadIdx.x;
    const int lane = tid & 63;
    const int w    = __builtin_amdgcn_readfirstlane(tid >> 6);
    const int valid  = vlens[b];
    const int nchunk = (valid + 63) >> 6;          // 1..4
    const int c    = (w + rot) & 3;
    if (c >= nchunk) return;                       // wave-uniform, retires now

    // sum(wv): uniform addresses -> scalar loads
    float sumwv;
    {
        f4 sw = {0.f, 0.f, 0.f, 0.f};
#pragma unroll
        for (int i = 0; i < 32; ++i) sw += ((const f4*)wv)[i];
        sumwv = (sw[0] + sw[1]) + (sw[2] + sw[3]);
    }

    const int q = (c << 6) + lane;
    const f4*    eqp = (const f4*)qE4 + (size_t)b * (32 * NQ_) + q;
    const float* ekp = kfE + ((size_t)(b * NK_ + k0)) * H_;   // uniform rows

    float acc[4];
#pragma unroll
    for (int k = 0; k < 4; ++k) acc[k] = 0.f;

#pragma unroll
    for (int half = 0; half < 2; ++half) {
        f4 eq[16];
#pragma unroll
        for (int i = 0; i < 16; ++i)
            eq[i] = eqp[(size_t)(half * 16 + i) * NQ_];
#pragma unroll
        for (int i = 0; i < 16; ++i) {
            const int h4 = (half * 16 + i) << 2;
            const f4 w4 = *(const f4*)(wv + h4);               // s_load
            const f4 e  = eq[i];
#pragma unroll
            for (int k = 0; k < 4; ++k) {
                const f4 ek = *(const f4*)(ekp + (size_t)k * H_ + h4);  // s_load
                acc[k] = fmaf(w4[0], rcp_fast(fmaf(ek[0], e[0], 1.f)), acc[k]);
                acc[k] = fmaf(w4[1], rcp_fast(fmaf(ek[1], e[1], 1.f)), acc[k]);
                acc[k] = fmaf(w4[2], rcp_fast(fmaf(ek[2], e[2], 1.f)), acc[k]);
                acc[k] = fmaf(w4[3], rcp_fast(fmaf(ek[3], e[3], 1.f)), acc[k]);
            }
        }
    }

    float* Ep = E + ((size_t)(b * NK_ + k0)) * NQ_ + q;
#pragma unroll
    for (int k = 0; k < 4; ++k) {
        const float s = sumwv - 2.f * acc[k];
        Ep[(size_t)k * NQ_] = (q < valid) ? exp2_fast(L2E * s) : 0.f;
    }
}

// ---------------------------------------------------------------------------
// Kernel B2: row-sum normalize + PV.  512 blocks x 256 threads, 8 k-rows.
// Stage E rows to LDS -> in-wave row sums -> PV with value read ONCE per
// block (8 k-accumulators/thread), 1/rowsum folded in at the end,
// LDS-atomic cross-wave reduce.
// ---------------------------------------------------------------------------
__global__ __launch_bounds__(256) void pv_kernel(
    const float* __restrict__ E, const float* __restrict__ value,
    const int* __restrict__ vlens, float* __restrict__ out)
{
    __shared__ alignas(16) float E_s[8 * 260];    // E rows (pad 260)
    __shared__ alignas(16) float red_s[8 * 256];  // reduction [k][d]
    __shared__ float inv_s[8];

    const int x    = blockIdx.x;
    const int qu   = x >> 7;                      // round 0..3
    const int xi   = x & 127;
    const int b    = (xi + (qu << 2)) & 15;
    const int kt   = (xi >> 4) + (qu << 3);       // 0..31
    const int k0   = kt << 3;
    const int tid  = threadIdx.x;
    const int w    = tid >> 6;
    const int lane = tid & 63;
    const int valid = vlens[b];

    // zero red_s; stage E rows (coalesced: 2 f4 per thread)
    ((f4*)red_s)[tid]       = (f4){0.f, 0.f, 0.f, 0.f};
    ((f4*)red_s)[tid + 256] = (f4){0.f, 0.f, 0.f, 0.f};
    {
        const int k  = tid >> 5;                  // 0..7
        const int q8 = (tid & 31) << 3;
        const f4* src = (const f4*)(E + ((size_t)(b * NK_ + k0 + k)) * NQ_ + q8);
        *(f4*)(E_s + k * 260 + q8)     = src[0];
        *(f4*)(E_s + k * 260 + q8 + 4) = src[1];
    }
    __syncthreads();

    // row sums (wave w -> rows 2w, 2w+1), masked at valid
#pragma unroll
    for (int kk = 0; kk < 2; ++kk) {
        const int k = (w << 1) + kk;
        const float* row = E_s + k * 260;
        float ssum = 0.f;
#pragma unroll
        for (int j = 0; j < 4; ++j) {
            const int q = (j << 6) + lane;
            ssum += (q < valid) ? row[q] : 0.f;
        }
#pragma unroll
        for (int off = 32; off >= 1; off >>= 1)
            ssum += __shfl_xor(ssum, off, 64);
        if (lane == 0) inv_s[k] = rcp_fast(ssum);
    }
    __syncthreads();

    // PV: wave w takes q = w (mod 4); 8 k-accumulators per thread
    {
        const int d4 = lane << 2;
        const float* vb = value + (size_t)b * (NQ_ * DV_) + d4;
        f4 o[8];
#pragma unroll
        for (int k = 0; k < 8; ++k) o[k] = (f4){0.f, 0.f, 0.f, 0.f};
#pragma unroll 2
        for (int q = w; q < valid; q += 4) {
            const f4 v = *(const f4*)(vb + (size_t)q * DV_);
#pragma unroll
            for (int k = 0; k < 8; ++k)
                o[k] += E_s[k * 260 + q] * v;     // uniform LDS broadcast
        }
#pragma unroll
        for (int k = 0; k < 8; ++k) {
            const f4 ok = o[k] * inv_s[k];
            float* p = red_s + (k << 8) + d4;
            atomicAdd(p + 0, ok[0]);
            atomicAdd(p + 1, ok[1]);
            atomicAdd(p + 2, ok[2]);
            atomicAdd(p + 3, ok[3]);
        }
    }
    __syncthreads();

    // store: 8 k x 64 f4 = 512 f4, 2 per thread
#pragma unroll
    for (int e = 0; e < 2; ++e) {
        const int i  = tid + (e << 8);
        const int k  = i >> 6;
        const int dd = (i & 63) << 2;
        f4 ov = *(const f4*)(red_s + (k << 8) + dd);
        *(f4*)(out + ((size_t)(b * NK_ + k0 + k)) * DV_ + dd) = ov;
    }
}

// ---------------------------------------------------------------------------
extern "C" void kernel_launch(void* const* d_in, const int* in_sizes, int n_in,
                              void* d_out, int out_size, void* d_ws, size_t ws_size,
                              hipStream_t stream)
{
    const float* key   = (const float*)d_in[0];
    const float* query = (const float*)d_in[1];
    const float* value = (const float*)d_in[2];
    const int*   vlens = (const int*)  d_in[3];
    const float* Wk    = (const float*)d_in[4];
    const float* Wq    = (const float*)d_in[5];
    const float* wv    = (const float*)d_in[6];
    float* outp = (float*)d_out;

    float* kfE = (float*)d_ws;                        // [B][NK][H]      2 MB
    float* qE4 = kfE + (size_t)B_ * NK_ * H_;         // [B][H/4][NQ][4] 2 MB
    float* E   = qE4 + (size_t)B_ * NQ_ * H_;         // [B][NK][NQ]     4 MB

    hipLaunchKernelGGL(proj_kernel, dim3(256), dim3(256), 0, stream,
                       key, query, Wk, Wq, kfE, qE4);
    hipLaunchKernelGGL(score_kernel, dim3(1024), dim3(256), 0, stream,
                       kfE, qE4, vlens, wv, E);
    hipLaunchKernelGGL(pv_kernel, dim3(512), dim3(256), 0, stream,
                       E, value, vlens, outp);
}

// Round 7
// 101.148 us; speedup vs baseline: 1.3807x; 1.3807x over previous
//
#include <hip/hip_runtime.h>

#define B_   16
#define NK_  256
#define NQ_  256
#define DK_  256
#define H_   128
#define DV_  256

// 2*log2(e): features prescaled so exp2(C2X*x) = e^{2x}
#define C2X 2.8853900817779268f
// log2(e) for softmax exp
#define L2E 1.4426950408889634f
#define MASKV -1.0e5f

typedef float f4 __attribute__((ext_vector_type(4)));

__device__ __forceinline__ float exp2_fast(float x) { return __builtin_amdgcn_exp2f(x); }
__device__ __forceinline__ float rcp_fast(float x)  { return __builtin_amdgcn_rcpf(x); }

// ---------------------------------------------------------------------------
// Kernel A: projections -> EXponentiated features.
// R7: 16-row blocks (512 total) instead of 32-row (256): grid was capping
// occupancy at 1 block/CU = 4 waves/CU; now 48 KB LDS -> 2 blocks/CU = 8
// waves/CU. Micro-tile 2 rows x 4 cols.
//   blocks 0..255   : kfE[b][k][h]      = exp2(C2X * (key  @ Wk))
//   blocks 256..511 : qE4[b][h/4][q][4] = exp2(C2X * (query @ Wq))
// ---------------------------------------------------------------------------
__global__ __launch_bounds__(256) void proj_kernel(
    const float* __restrict__ key, const float* __restrict__ query,
    const float* __restrict__ Wk,  const float* __restrict__ Wq,
    float* __restrict__ kfE, float* __restrict__ qE4)
{
    __shared__ alignas(16) float A_s[16 * 256];   // 16 KB
    __shared__ alignas(16) float W_s[64 * 128];   // 32 KB

    const int blk = blockIdx.x;
    const int tid = threadIdx.x;
    const bool isQ = blk >= 256;
    const int rb = (blk & 255) * 16;              // flat row base (b*256 + row)

    const float* __restrict__ A = isQ ? query : key;
    const float* __restrict__ W = isQ ? Wq : Wk;

    // stage 16 x 256 input rows (coalesced float4, 4 per thread)
    {
        const f4* src = (const f4*)(A + (size_t)rb * DK_);
        f4* dst = (f4*)A_s;
#pragma unroll
        for (int j = 0; j < 4; ++j) dst[tid + 256 * j] = src[tid + 256 * j];
    }

    const int rg2 = (tid >> 5) << 1;              // row base: 2 rows
    const int c4  = (tid & 31) << 2;              // col base: 4 cols

    f4 acc0 = {0.f, 0.f, 0.f, 0.f}, acc1 = acc0;

    for (int kc = 0; kc < DK_; kc += 64) {
        __syncthreads();                          // A_s staged / prev W reads done
        {
            const f4* wsrc = (const f4*)(W + (size_t)kc * H_);
            f4* wdst = (f4*)W_s;
#pragma unroll
            for (int j = 0; j < 8; ++j) wdst[tid + 256 * j] = wsrc[tid + 256 * j];
        }
        __syncthreads();
#pragma unroll 2
        for (int k = 0; k < 64; k += 4) {
            f4 w0 = *(const f4*)(W_s + (k + 0) * H_ + c4);
            f4 w1 = *(const f4*)(W_s + (k + 1) * H_ + c4);
            f4 w2 = *(const f4*)(W_s + (k + 2) * H_ + c4);
            f4 w3 = *(const f4*)(W_s + (k + 3) * H_ + c4);
            f4 a0 = *(const f4*)(A_s + (rg2 + 0) * 256 + kc + k);
            f4 a1 = *(const f4*)(A_s + (rg2 + 1) * 256 + kc + k);
            acc0 += a0[0] * w0; acc1 += a1[0] * w0;
            acc0 += a0[1] * w1; acc1 += a1[1] * w1;
            acc0 += a0[2] * w2; acc1 += a1[2] * w2;
            acc0 += a0[3] * w3; acc1 += a1[3] * w3;
        }
    }

    f4 e0, e1;
#pragma unroll
    for (int cc = 0; cc < 4; ++cc) {
        e0[cc] = exp2_fast(C2X * acc0[cc]);
        e1[cc] = exp2_fast(C2X * acc1[cc]);
    }

    if (!isQ) {
        float* dst = kfE + (size_t)(rb + rg2) * H_ + c4;
        *(f4*)(dst)      = e0;
        *(f4*)(dst + H_) = e1;
    } else {
        const int b  = rb >> 8;
        const int q0 = (rb & 255) + rg2;
        f4* dst = (f4*)qE4 + ((size_t)(b * 32 + (c4 >> 2))) * NQ_ + q0;
        dst[0] = e0;                              // query q0   : 4 h-values
        dst[1] = e1;                              // query q0+1
    }
}

// ---------------------------------------------------------------------------
// Kernel B: fused scores + masked softmax + PV.  1024 blocks x 256 threads,
// 4 k-rows/block (R5 skeleton: all 4096 waves always active).
// R7 phase 1: wave w -> 2 k-rows {k0+2(w>>1), +1}, chunks j == (w&1) mod 2.
// Each eq f4 load feeds 2 rows (8 rcp / load) -> eq L2 traffic halved.
// Scores via sc_s (R3-proven); phase 2 softmax per k-row per wave; phase 3
// value-read-once PV with LDS reduce (R5 verbatim).
// ---------------------------------------------------------------------------
__global__ __launch_bounds__(256) void attn_kernel(
    const float* __restrict__ kfE, const float* __restrict__ qE4,
    const float* __restrict__ value, const int* __restrict__ vlens,
    const float* __restrict__ wv, float* __restrict__ out)
{
    __shared__ alignas(16) float sc_s[4 * 260];    // scores [k][q] (pad 260)
    __shared__ alignas(16) float at4_s[256 * 4];   // attn transposed [q][k]
    __shared__ alignas(16) float red_s[16 * 256];  // phase-3 partials

    const int x    = blockIdx.x;
    const int qu   = x >> 8;                       // dispatch round 0..3
    const int xi   = x & 255;
    const int b    = (xi + (qu << 2)) & 15;        // b rotated for balance
    const int kt   = (xi >> 4) + (qu << 4);        // 0..63
    const int k0   = kt << 2;
    const int tid  = threadIdx.x;
    const int lane = tid & 63;
    const int wu   = __builtin_amdgcn_readfirstlane(tid >> 6);
    const int valid  = vlens[b];
    const int nchunk = (valid + 63) >> 6;          // 1..4

    // sum(wv): uniform addresses -> scalar loads
    float sumwv;
    {
        f4 sw = {0.f, 0.f, 0.f, 0.f};
#pragma unroll
        for (int i = 0; i < 32; ++i) sw += ((const f4*)wv)[i];
        sumwv = (sw[0] + sw[1]) + (sw[2] + sw[3]);
    }

    // ---- Phase 1: wave = (row pair p, chunk parity par).
    {
        const int p   = wu >> 1;
        const int par = wu & 1;
        const int l0  = p << 1;                    // local rows l0, l0+1
        // active chunk slots: j = par, par+2  (j < nchunk)
        const int nslot = (par < nchunk ? 1 : 0) + (par + 2 < nchunk ? 1 : 0);

        if (nslot) {
            const float* ekp = kfE + ((size_t)(b * NK_ + k0 + l0)) * H_; // uniform
            const f4*    eqA = (const f4*)qE4 + (size_t)b * (32 * NQ_)
                               + ((par << 6) + lane);
            const f4*    eqB = eqA + 128;          // chunk par+2

            // acc[slot][row][chain]
            float acc[2][2][2];
#pragma unroll
            for (int s = 0; s < 2; ++s)
#pragma unroll
                for (int r = 0; r < 2; ++r) { acc[s][r][0] = 0.f; acc[s][r][1] = 0.f; }

            auto body = [&](int NS) {
#pragma unroll 4
                for (int h4 = 0; h4 < 32; ++h4) {
                    const f4 ekA = *(const f4*)(ekp + (h4 << 2));        // s_load
                    const f4 ekB = *(const f4*)(ekp + H_ + (h4 << 2));   // s_load
                    const f4 w4  = *(const f4*)(wv + (h4 << 2));         // s_load
                    {
                        const f4 e = eqA[(size_t)h4 * NQ_];
                        acc[0][0][0] = fmaf(w4[0], rcp_fast(fmaf(ekA[0], e[0], 1.f)), acc[0][0][0]);
                        acc[0][0][1] = fmaf(w4[1], rcp_fast(fmaf(ekA[1], e[1], 1.f)), acc[0][0][1]);
                        acc[0][0][0] = fmaf(w4[2], rcp_fast(fmaf(ekA[2], e[2], 1.f)), acc[0][0][0]);
                        acc[0][0][1] = fmaf(w4[3], rcp_fast(fmaf(ekA[3], e[3], 1.f)), acc[0][0][1]);
                        acc[0][1][0] = fmaf(w4[0], rcp_fast(fmaf(ekB[0], e[0], 1.f)), acc[0][1][0]);
                        acc[0][1][1] = fmaf(w4[1], rcp_fast(fmaf(ekB[1], e[1], 1.f)), acc[0][1][1]);
                        acc[0][1][0] = fmaf(w4[2], rcp_fast(fmaf(ekB[2], e[2], 1.f)), acc[0][1][0]);
                        acc[0][1][1] = fmaf(w4[3], rcp_fast(fmaf(ekB[3], e[3], 1.f)), acc[0][1][1]);
                    }
                    if (NS == 2) {
                        const f4 e = eqB[(size_t)h4 * NQ_];
                        acc[1][0][0] = fmaf(w4[0], rcp_fast(fmaf(ekA[0], e[0], 1.f)), acc[1][0][0]);
                        acc[1][0][1] = fmaf(w4[1], rcp_fast(fmaf(ekA[1], e[1], 1.f)), acc[1][0][1]);
                        acc[1][0][0] = fmaf(w4[2], rcp_fast(fmaf(ekA[2], e[2], 1.f)), acc[1][0][0]);
                        acc[1][0][1] = fmaf(w4[3], rcp_fast(fmaf(ekA[3], e[3], 1.f)), acc[1][0][1]);
                        acc[1][1][0] = fmaf(w4[0], rcp_fast(fmaf(ekB[0], e[0], 1.f)), acc[1][1][0]);
                        acc[1][1][1] = fmaf(w4[1], rcp_fast(fmaf(ekB[1], e[1], 1.f)), acc[1][1][1]);
                        acc[1][1][0] = fmaf(w4[2], rcp_fast(fmaf(ekB[2], e[2], 1.f)), acc[1][1][0]);
                        acc[1][1][1] = fmaf(w4[3], rcp_fast(fmaf(ekB[3], e[3], 1.f)), acc[1][1][1]);
                    }
                }
            };
            if (nslot == 1) body(1); else body(2);

#pragma unroll
            for (int s = 0; s < 2; ++s) {
                if (s < nslot) {
                    const int q = (((par + (s << 1))) << 6) + lane;
                    sc_s[(l0 + 0) * 260 + q] = sumwv - 2.f * (acc[s][0][0] + acc[s][0][1]);
                    sc_s[(l0 + 1) * 260 + q] = sumwv - 2.f * (acc[s][1][0] + acc[s][1][1]);
                }
            }
        }
    }
    __syncthreads();

    // ---- Phase 2: in-wave masked softmax, wave wu -> k-row wu.
    {
        const float* row = sc_s + wu * 260;
        float s[4];
        float m = MASKV;
#pragma unroll
        for (int j = 0; j < 4; ++j) {
            const int q = (j << 6) + lane;
            s[j] = (q < valid) ? row[q] : MASKV;
            m = fmaxf(m, s[j]);
        }
#pragma unroll
        for (int off = 32; off >= 1; off >>= 1)
            m = fmaxf(m, __shfl_xor(m, off, 64));
        float ssum = 0.f;
#pragma unroll
        for (int j = 0; j < 4; ++j) {
            s[j] = exp2_fast(L2E * (s[j] - m));   // masked -> 0
            ssum += s[j];
        }
#pragma unroll
        for (int off = 32; off >= 1; off >>= 1)
            ssum += __shfl_xor(ssum, off, 64);
        const float inv = rcp_fast(ssum);
#pragma unroll
        for (int j = 0; j < 4; ++j)
            at4_s[(((j << 6) + lane) << 2) + wu] = s[j] * inv;
    }
    __syncthreads();

    // ---- Phase 3: out[b][k0+k][d] = sum_q attn[q][k] * value[b][q][d]
    {
        const int rq = tid >> 6;
        const int d4 = lane << 2;
        const float* vb = value + (size_t)b * (NQ_ * DV_) + d4;
        f4 o0 = {0.f,0.f,0.f,0.f}, o1 = o0, o2 = o0, o3 = o0;
#pragma unroll 4
        for (int q = rq; q < valid; q += 4) {
            f4 v  = *(const f4*)(vb + (size_t)q * DV_);
            f4 a4 = *(const f4*)(at4_s + (q << 2));   // uniform b128 broadcast
            o0 += a4[0] * v;
            o1 += a4[1] * v;
            o2 += a4[2] * v;
            o3 += a4[3] * v;
        }
        float* rs = red_s + (rq << 10) + d4;          // red_s[rq*4+k][256]
        *(f4*)(rs + 0)    = o0;
        *(f4*)(rs + 256)  = o1;
        *(f4*)(rs + 512)  = o2;
        *(f4*)(rs + 768)  = o3;
    }
    __syncthreads();

    // cross-wave reduce + store
    {
        const int k  = tid >> 6;
        const int d4 = lane << 2;
        const float* rs = red_s + (k << 8) + d4;
        f4 o = *(const f4*)(rs) + *(const f4*)(rs + 1024)
             + *(const f4*)(rs + 2048) + *(const f4*)(rs + 3072);
        *(f4*)(out + ((size_t)(b * NK_ + k0 + k)) * DV_ + d4) = o;
    }
}

// ---------------------------------------------------------------------------
extern "C" void kernel_launch(void* const* d_in, const int* in_sizes, int n_in,
                              void* d_out, int out_size, void* d_ws, size_t ws_size,
                              hipStream_t stream)
{
    const float* key   = (const float*)d_in[0];
    const float* query = (const float*)d_in[1];
    const float* value = (const float*)d_in[2];
    const int*   vlens = (const int*)  d_in[3];
    const float* Wk    = (const float*)d_in[4];
    const float* Wq    = (const float*)d_in[5];
    const float* wv    = (const float*)d_in[6];
    float* outp = (float*)d_out;

    float* kfE = (float*)d_ws;                        // [B][NK][H]      2 MB
    float* qE4 = kfE + (size_t)B_ * NK_ * H_;         // [B][H/4][NQ][4] 2 MB

    hipLaunchKernelGGL(proj_kernel, dim3(512), dim3(256), 0, stream,
                       key, query, Wk, Wq, kfE, qE4);
    hipLaunchKernelGGL(attn_kernel, dim3(1024), dim3(256), 0, stream,
                       kfE, qE4, value, vlens, wv, outp);
}